// Round 4
// baseline (2453.357 us; speedup 1.0000x reference)
//
#include <hip/hip_runtime.h>

// SOSA forward — round 4: L3-resident working set + depth-2 prefetch pipeline.
// Symmetric Gram-domain NS (all iterates are polynomials of G=WW^T -> symmetric,
// B^T == B). Split-3 bf16 (P = Ah@Bh + Ah@Bl + Al@Bh, fp32 accum).
// Round-4 changes:
//  - slot renaming: y'->u-slot, z'->t-slot (t only read as own-idx epilogue term)
//    => 12 NN arrays + W per batch = 7.9 MB; NB=32 => ~252 MB working set < 256 MB L3.
//  - GEMM K-loop prefetch depth 2 (reg-staged): STAGE(s+2) issued before MFMA(s).

typedef unsigned short u16;
typedef unsigned int u32;
typedef short bf16x8 __attribute__((ext_vector_type(8)));
typedef float f32x4 __attribute__((ext_vector_type(4)));

#define B_  64
#define C_  512
#define D_  784
#define DP_ 800
#define NN_ ((size_t)C_ * C_)   // 262144
#define WN_ ((size_t)C_ * DP_)  // 409600
#define NBMAX 32

__device__ inline u16 f2bf(float f) {
    u32 u = __builtin_bit_cast(u32, f);
    u += 0x7fffu + ((u >> 16) & 1u);
    return (u16)(u >> 16);
}
__device__ inline float bf2f(u16 h) {
    u32 u = ((u32)h) << 16;
    return __builtin_bit_cast(float, u);
}

// ---------------------------------------------------------------- small ops
__global__ __launch_bounds__(64) void zero_kernel(float* __restrict__ p, int n) {
    int i = blockIdx.x * 64 + threadIdx.x;
    if (i < n) p[i] = 0.f;
}

__global__ __launch_bounds__(256) void mu_kernel(const float* __restrict__ X,
                                                 float* __restrict__ mu,
                                                 float* __restrict__ ssq) {
    int b = blockIdx.y;
    int i = blockIdx.x * 256 + threadIdx.x;
    float s = 0.f, q = 0.f;
    if (i < D_) {
        const float* xb = X + (size_t)b * C_ * D_ + i;
        for (int c = 0; c < C_; ++c) { float v = xb[(size_t)c * D_]; s += v; q += v * v; }
        mu[b * D_ + i] = s * (1.f / C_);
    }
    __shared__ float red[256];
    red[threadIdx.x] = q;
    __syncthreads();
    for (int off = 128; off > 0; off >>= 1) {
        if (threadIdx.x < off) red[threadIdx.x] += red[threadIdx.x + off];
        __syncthreads();
    }
    if (threadIdx.x == 0) atomicAdd(&ssq[b], red[0]);
}

__global__ __launch_bounds__(256) void rfro_kernel(const float* __restrict__ mu,
                                                   const float* __restrict__ ssq,
                                                   float* __restrict__ rfro) {
    int b = blockIdx.x;
    float q = 0.f;
    for (int i = threadIdx.x; i < D_; i += 256) { float m = mu[b * D_ + i]; q += m * m; }
    __shared__ float red[256];
    red[threadIdx.x] = q;
    __syncthreads();
    for (int off = 128; off > 0; off >>= 1) {
        if (threadIdx.x < off) red[threadIdx.x] += red[threadIdx.x + off];
        __syncthreads();
    }
    if (threadIdx.x == 0) rfro[b] = rsqrtf(ssq[b] - (float)C_ * red[0]);
}

// W = (X - mu) * rfro, split hi/lo bf16, cols 784..799 zero.
__global__ __launch_bounds__(256) void wbuild_kernel(const float* __restrict__ X,
                                                     const float* __restrict__ mu,
                                                     const float* __restrict__ rfro,
                                                     u16* __restrict__ Wh, u16* __restrict__ Wl,
                                                     int b0, int bc) {
    size_t idx = (size_t)blockIdx.x * 256 + threadIdx.x;
    size_t total = (size_t)bc * C_ * (DP_ / 8);
    if (idx >= total) return;
    int ch = (int)(idx % (DP_ / 8));
    size_t rest = idx / (DP_ / 8);
    int c = (int)(rest % C_);
    int bz = (int)(rest / C_);
    int b = b0 + bz;
    int i0 = ch * 8;
    u32 hw[4] = {0, 0, 0, 0}, lw[4] = {0, 0, 0, 0};
    if (i0 < D_) {
        float rf = rfro[b];
        const float* xr = X + ((size_t)b * C_ + c) * D_ + i0;
        const float* mr = mu + (size_t)b * D_ + i0;
#pragma unroll
        for (int e2 = 0; e2 < 4; ++e2) {
            float v0 = (xr[2 * e2] - mr[2 * e2]) * rf;
            float v1 = (xr[2 * e2 + 1] - mr[2 * e2 + 1]) * rf;
            u16 h0 = f2bf(v0), h1 = f2bf(v1);
            u16 l0 = f2bf(v0 - bf2f(h0)), l1 = f2bf(v1 - bf2f(h1));
            hw[e2] = (u32)h0 | ((u32)h1 << 16);
            lw[e2] = (u32)l0 | ((u32)l1 << 16);
        }
    }
    size_t o = ((size_t)bz * C_ + c) * DP_ + i0;
    uint4 ph; ph.x = hw[0]; ph.y = hw[1]; ph.z = hw[2]; ph.w = hw[3];
    uint4 pl; pl.x = lw[0]; pl.y = lw[1]; pl.z = lw[2]; pl.w = lw[3];
    *(uint4*)&Wh[o] = ph;
    *(uint4*)&Wl[o] = pl;
}

// z0 = -0.5 I, vectorized by 8
__global__ __launch_bounds__(256) void z0init_kernel(u16* __restrict__ zh, u16* __restrict__ zl,
                                                     int bc) {
    size_t i8 = (size_t)blockIdx.x * 256 + threadIdx.x;
    size_t tot = (size_t)bc * NN_ / 8;
    if (i8 >= tot) return;
    size_t e0 = i8 * 8;
    int r = (int)((e0 >> 9) & 511);
    int c0 = (int)(e0 & 511);
    u32 w[4] = {0, 0, 0, 0};
    int dj = r - c0;
    if (dj >= 0 && dj < 8) w[dj >> 1] |= ((u32)0xBF00u) << ((dj & 1) * 16);
    uint4 ph; ph.x = w[0]; ph.y = w[1]; ph.z = w[2]; ph.w = w[3];
    uint4 zzero; zzero.x = 0; zzero.y = 0; zzero.z = 0; zzero.w = 0;
    *(uint4*)&zh[e0] = ph;
    *(uint4*)&zl[e0] = zzero;
}

// avec[b,c] = (1/d) sum_i W[c,i]
__global__ __launch_bounds__(128) void arowsum_kernel(const u16* __restrict__ Wh,
                                                      const u16* __restrict__ Wl,
                                                      float* __restrict__ avec, int b0) {
    int c = blockIdx.x, bz = blockIdx.y;
    const u16* wh = Wh + ((size_t)bz * C_ + c) * DP_;
    const u16* wl = Wl + ((size_t)bz * C_ + c) * DP_;
    float s = 0.f;
    for (int i = threadIdx.x; i < DP_; i += 128) s += bf2f(wh[i]) + bf2f(wl[i]);
    __shared__ float red[128];
    red[threadIdx.x] = s;
    __syncthreads();
    for (int off = 64; off > 0; off >>= 1) {
        if (threadIdx.x < off) red[threadIdx.x] += red[threadIdx.x + off];
        __syncthreads();
    }
    if (threadIdx.x == 0) avec[(size_t)(b0 + bz) * C_ + c] = red[0] * (1.f / D_);
}

// r1[b,c] = sum_j y[c,j]*avec[b,j]
__global__ __launch_bounds__(128) void ra_kernel(const u16* __restrict__ yh,
                                                 const u16* __restrict__ yl,
                                                 const float* __restrict__ avec,
                                                 float* __restrict__ r1, int b0) {
    int c = blockIdx.x, bz = blockIdx.y;
    int b = b0 + bz;
    const u16* ph = yh + (size_t)bz * NN_ + (size_t)c * C_;
    const u16* pl = yl + (size_t)bz * NN_ + (size_t)c * C_;
    const float* av = avec + (size_t)b * C_;
    float s = 0.f;
    for (int j = threadIdx.x; j < C_; j += 128) s += (bf2f(ph[j]) + bf2f(pl[j])) * av[j];
    __shared__ float red[128];
    red[threadIdx.x] = s;
    __syncthreads();
    for (int off = 64; off > 0; off >>= 1) {
        if (threadIdx.x < off) red[threadIdx.x] += red[threadIdx.x + off];
        __syncthreads();
    }
    if (threadIdx.x == 0) r1[(size_t)b * C_ + c] = red[0];
}

// w2[b,j] = 1.5*r1[b,j] + sum_c v[j,c]*r1[b,c]
__global__ __launch_bounds__(128) void w2_kernel(const u16* __restrict__ vh,
                                                 const u16* __restrict__ vl,
                                                 const float* __restrict__ r1,
                                                 float* __restrict__ w2, int b0) {
    int j = blockIdx.x, bz = blockIdx.y;
    int b = b0 + bz;
    const u16* ph = vh + (size_t)bz * NN_ + (size_t)j * C_;
    const u16* pl = vl + (size_t)bz * NN_ + (size_t)j * C_;
    const float* r = r1 + (size_t)b * C_;
    float s = 0.f;
    for (int c = threadIdx.x; c < C_; c += 128) s += (bf2f(ph[c]) + bf2f(pl[c])) * r[c];
    __shared__ float red[128];
    red[threadIdx.x] = s;
    __syncthreads();
    for (int off = 64; off > 0; off >>= 1) {
        if (threadIdx.x < off) red[threadIdx.x] += red[threadIdx.x + off];
        __syncthreads();
    }
    if (threadIdx.x == 0) w2[(size_t)b * C_ + j] = 1.5f * r[j] + red[0];
}

// svec[b,j] = sum_c w2[b,c]*W[c,j]
__global__ __launch_bounds__(256) void svec_kernel(const float* __restrict__ w2,
                                                   const u16* __restrict__ Wh,
                                                   const u16* __restrict__ Wl,
                                                   float* __restrict__ svec, int b0) {
    int bz = blockIdx.y;
    int j = blockIdx.x * 256 + threadIdx.x;
    if (j >= D_) return;
    const u16* wh = Wh + (size_t)bz * WN_;
    const u16* wl = Wl + (size_t)bz * WN_;
    const float* w = w2 + (size_t)(b0 + bz) * C_;
    float s = 0.f;
    for (int c = 0; c < C_; ++c) s += w[c] * (bf2f(wh[(size_t)c * DP_ + j]) + bf2f(wl[(size_t)c * DP_ + j]));
    svec[(size_t)(b0 + bz) * D_ + j] = s;
}

__global__ __launch_bounds__(256) void minmax_kernel(const float* __restrict__ s,
                                                     float* __restrict__ ycov, int b0) {
    int b = b0 + blockIdx.x;
    const float* sb = s + (size_t)b * D_;
    float mn = 1e30f, mx = -1e30f;
    for (int i = threadIdx.x; i < D_; i += 256) {
        float v = sb[i];
        mn = fminf(mn, v);
        mx = fmaxf(mx, v);
    }
    __shared__ float rmn[256], rmx[256];
    rmn[threadIdx.x] = mn;
    rmx[threadIdx.x] = mx;
    __syncthreads();
    for (int off = 128; off > 0; off >>= 1) {
        if (threadIdx.x < off) {
            rmn[threadIdx.x] = fminf(rmn[threadIdx.x], rmn[threadIdx.x + off]);
            rmx[threadIdx.x] = fmaxf(rmx[threadIdx.x], rmx[threadIdx.x + off]);
        }
        __syncthreads();
    }
    float gmn = rmn[0], gmx = rmx[0];
    float inv = 1.f / (gmx - gmn);
    for (int i = threadIdx.x; i < D_; i += 256)
        ycov[(size_t)b * D_ + i] = (sb[i] - gmn) * inv;
}

__global__ __launch_bounds__(256) void scale_kernel(const float* __restrict__ X,
                                                    const float* __restrict__ ycov,
                                                    float* __restrict__ out) {
    size_t idx = (size_t)blockIdx.x * 256 + threadIdx.x;
    size_t n = idx * 4;
    if (n >= (size_t)B_ * C_ * D_) return;
    int b = (int)(n / ((size_t)C_ * D_));
    int i = (int)(n % D_);
    float4 x4 = *(const float4*)(X + n);
    float4 y4 = *(const float4*)(ycov + (size_t)b * D_ + i);
    float4 o;
    o.x = x4.x * y4.x; o.y = x4.y * y4.y; o.z = x4.z * y4.z; o.w = x4.w * y4.w;
    *(float4*)(out + n) = o;
}

// ---------------------------------------------------------------- MFMA GEMM
// C(512x512)[bz] = alpha*(A@B) + diagv*I + beta*E1 + gamma*E2 (B symmetric ->
// staged by rows). Split-3 bf16. 128^2 tile, 4 waves (64x64), BK=32,
// double-buffered LDS, reg-staged prefetch depth 2.
__global__ __launch_bounds__(256, 2) void gemm_ns(
    const u16* __restrict__ Ah, const u16* __restrict__ Al, int ldA, size_t sA,
    const u16* __restrict__ Bh, const u16* __restrict__ Bl, int ldB, size_t sB,
    int K,
    float alpha, float diagv,
    const u16* __restrict__ E1h, const u16* __restrict__ E1l, float beta,
    const u16* __restrict__ E2h, const u16* __restrict__ E2l, float gamma,
    u16* __restrict__ O1h, u16* __restrict__ O1l,
    float alpha2, float diag2,
    u16* __restrict__ O2h, u16* __restrict__ O2l)
{
    __shared__ u16 lds[2][4][128][36];   // dbuf x {Ah,Al,Bh,Bl} x rows x (32+4 pad)
    int bz = blockIdx.z;
    int t = threadIdx.x;
    int lane = t & 63, wid = t >> 6;
    int wr = wid >> 1, wc = wid & 1;
    int row0 = blockIdx.y * 128, col0 = blockIdx.x * 128;
    const u16* pA0 = Ah + (size_t)bz * sA;
    const u16* pA1 = Al + (size_t)bz * sA;
    const u16* pB0 = Bh + (size_t)bz * sB;
    const u16* pB1 = Bl + (size_t)bz * sB;
    int lr = t >> 2, lkc = (t & 3) * 8;   // loader: rows lr, lr+64; 8-elem k-chunk
    f32x4 acc[4][4] = {};
    uint4 rg0, rg1, rg2, rg3, rg4, rg5, rg6, rg7;

#define STAGE(k0) do { \
    rg0 = *(const uint4*)&pA0[(size_t)(row0 + lr) * ldA + (k0) + lkc]; \
    rg1 = *(const uint4*)&pA0[(size_t)(row0 + lr + 64) * ldA + (k0) + lkc]; \
    rg2 = *(const uint4*)&pA1[(size_t)(row0 + lr) * ldA + (k0) + lkc]; \
    rg3 = *(const uint4*)&pA1[(size_t)(row0 + lr + 64) * ldA + (k0) + lkc]; \
    rg4 = *(const uint4*)&pB0[(size_t)(col0 + lr) * ldB + (k0) + lkc]; \
    rg5 = *(const uint4*)&pB0[(size_t)(col0 + lr + 64) * ldB + (k0) + lkc]; \
    rg6 = *(const uint4*)&pB1[(size_t)(col0 + lr) * ldB + (k0) + lkc]; \
    rg7 = *(const uint4*)&pB1[(size_t)(col0 + lr + 64) * ldB + (k0) + lkc]; \
} while (0)
#define WLDS(bf) do { \
    *(uint4*)&lds[bf][0][lr][lkc] = rg0; \
    *(uint4*)&lds[bf][0][lr + 64][lkc] = rg1; \
    *(uint4*)&lds[bf][1][lr][lkc] = rg2; \
    *(uint4*)&lds[bf][1][lr + 64][lkc] = rg3; \
    *(uint4*)&lds[bf][2][lr][lkc] = rg4; \
    *(uint4*)&lds[bf][2][lr + 64][lkc] = rg5; \
    *(uint4*)&lds[bf][3][lr][lkc] = rg6; \
    *(uint4*)&lds[bf][3][lr + 64][lkc] = rg7; \
} while (0)

    STAGE(0);
    WLDS(0);          // compiler inserts vmcnt wait for rg*
    STAGE(32);        // prefetch step 1 while step 0 already in LDS
    __syncthreads();

    int nst = K >> 5;
    for (int s = 0; s < nst; ++s) {
        int cur = s & 1;
        if (s + 1 < nst) WLDS(cur ^ 1);       // regs hold step s+1 (issued 1 iter ago)
        if (s + 2 < nst) STAGE((s + 2) * 32); // issue loads 2 steps ahead
        int koff = (lane >> 4) * 8;
        int fr = lane & 15;
        bf16x8 bhf[4], blf[4];
#pragma unroll
        for (int n = 0; n < 4; ++n) {
            int rB = wc * 64 + n * 16 + fr;
            bhf[n] = *(const bf16x8*)&lds[cur][2][rB][koff];
            blf[n] = *(const bf16x8*)&lds[cur][3][rB][koff];
        }
#pragma unroll
        for (int m = 0; m < 4; ++m) {
            int rA = wr * 64 + m * 16 + fr;
            bf16x8 ah = *(const bf16x8*)&lds[cur][0][rA][koff];
            bf16x8 al = *(const bf16x8*)&lds[cur][1][rA][koff];
#pragma unroll
            for (int n = 0; n < 4; ++n) {
                acc[m][n] = __builtin_amdgcn_mfma_f32_16x16x32_bf16(ah, bhf[n], acc[m][n], 0, 0, 0);
                acc[m][n] = __builtin_amdgcn_mfma_f32_16x16x32_bf16(ah, blf[n], acc[m][n], 0, 0, 0);
                acc[m][n] = __builtin_amdgcn_mfma_f32_16x16x32_bf16(al, bhf[n], acc[m][n], 0, 0, 0);
            }
        }
        if (s + 1 < nst) __syncthreads();
    }
#undef STAGE
#undef WLDS

    // epilogue: row-major writes only (outputs symmetric)
    size_t eoff = (size_t)bz * NN_;
    const u16* e1h = E1h ? E1h + eoff : (const u16*)0;
    const u16* e1l = E1l ? E1l + eoff : (const u16*)0;
    const u16* e2h = E2h ? E2h + eoff : (const u16*)0;
    const u16* e2l = E2l ? E2l + eoff : (const u16*)0;
    u16* o1h = O1h + eoff;
    u16* o1l = O1l + eoff;
    u16* o2h = O2h ? O2h + eoff : (u16*)0;
    u16* o2l = O2l ? O2l + eoff : (u16*)0;
    int rBase = row0 + wr * 64 + (lane >> 4) * 4;
    int cBase = col0 + wc * 64 + (lane & 15);
#pragma unroll
    for (int m = 0; m < 4; ++m) {
#pragma unroll
        for (int n = 0; n < 4; ++n) {
            int cg = cBase + n * 16;
#pragma unroll
            for (int q = 0; q < 4; ++q) {
                int r = rBase + m * 16 + q;
                size_t idx = ((size_t)r << 9) + cg;
                float P = acc[m][n][q];
                float val = alpha * P;
                if (r == cg) val += diagv;
                if (e1h) val += beta * (bf2f(e1h[idx]) + bf2f(e1l[idx]));
                if (e2h) val += gamma * (bf2f(e2h[idx]) + bf2f(e2l[idx]));
                u16 h = f2bf(val);
                o1h[idx] = h;
                o1l[idx] = f2bf(val - bf2f(h));
                if (o2h) {
                    float v2 = alpha2 * P;
                    if (r == cg) v2 += diag2;
                    u16 h2 = f2bf(v2);
                    o2h[idx] = h2;
                    o2l[idx] = f2bf(v2 - bf2f(h2));
                }
            }
        }
    }
}

// ---------------------------------------------------------------- host
static inline void launch_gemm(hipStream_t st, int bc,
    const u16* Ah, const u16* Al, int ldA, size_t sA,
    const u16* Bh, const u16* Bl, int ldB, size_t sB, int K,
    float alpha, float diagv,
    const u16* E1h, const u16* E1l, float beta,
    const u16* E2h, const u16* E2l, float gamma,
    u16* O1h, u16* O1l,
    float alpha2, float diag2, u16* O2h, u16* O2l)
{
    gemm_ns<<<dim3(4, 4, bc), 256, 0, st>>>(Ah, Al, ldA, sA, Bh, Bl, ldB, sB, K,
        alpha, diagv, E1h, E1l, beta, E2h, E2l, gamma,
        O1h, O1l, alpha2, diag2, O2h, O2l);
}

extern "C" void kernel_launch(void* const* d_in, const int* in_sizes, int n_in,
                              void* d_out, int out_size, void* d_ws, size_t ws_size,
                              hipStream_t stream) {
    const float* X = (const float*)d_in[0];
    float* out = (float*)d_out;
    float* hdr = (float*)d_ws;

    float* mu   = hdr;
    float* ssq  = mu + (size_t)B_ * D_;
    float* rfro = ssq + B_;
    float* avec = rfro + B_;
    float* r1v  = avec + (size_t)B_ * C_;
    float* w2v  = r1v + (size_t)B_ * C_;
    float* svec = w2v + (size_t)B_ * C_;
    float* ycov = svec + (size_t)B_ * D_;
    size_t hdrBytes = (size_t)((char*)(ycov + (size_t)B_ * D_) - (char*)hdr);
    size_t matsOff = (hdrBytes + 255) & ~(size_t)255;

    const size_t perBatch = (2 * WN_ + 12 * NN_) * 2;   // bytes (~7.9 MB)
    size_t avail = ws_size > matsOff ? ws_size - matsOff : 0;
    int NB = (int)(avail / perBatch);
    if (NB < 1) NB = 1;
    if (NB > NBMAX) NB = NBMAX;

    u16* q = (u16*)((char*)d_ws + matsOff);
    u16* Wh = q; q += (size_t)NB * WN_;
    u16* Wl = q; q += (size_t)NB * WN_;
    u16* Gh = q; q += (size_t)NB * NN_;
    u16* Gl = q; q += (size_t)NB * NN_;
    u16* slot[5][2];
    for (int s = 0; s < 5; ++s)
        for (int a = 0; a < 2; ++a) { slot[s][a] = q; q += (size_t)NB * NN_; }

    zero_kernel<<<1, 64, 0, stream>>>(ssq, B_);
    mu_kernel<<<dim3((D_ + 255) / 256, B_), 256, 0, stream>>>(X, mu, ssq);
    rfro_kernel<<<B_, 256, 0, stream>>>(mu, ssq, rfro);

    for (int b0 = 0; b0 < B_; b0 += NB) {
        int bc = (B_ - b0 < NB) ? (B_ - b0) : NB;

        size_t wbTotal = (size_t)bc * C_ * (DP_ / 8);
        wbuild_kernel<<<(unsigned)((wbTotal + 255) / 256), 256, 0, stream>>>(X, mu, rfro, Wh, Wl, b0, bc);

        // slot roles (rotate via renaming each iteration)
        int iy = 0, iz = 1, it = 2, iu = 3, iv = 4;

        size_t ziTotal = (size_t)bc * NN_ / 8;
        z0init_kernel<<<(unsigned)((ziTotal + 255) / 256), 256, 0, stream>>>(slot[iz][0], slot[iz][1], bc);
        arowsum_kernel<<<dim3(C_, bc), 128, 0, stream>>>(Wh, Wl, avec, b0);

        // SYRK: G = W W^T ; second output y0 = 1.5 I - 0.5 G
        launch_gemm(stream, bc, Wh, Wl, DP_, WN_, Wh, Wl, DP_, WN_, DP_,
                    1.f, 0.f, 0, 0, 0.f, 0, 0, 0.f,
                    Gh, Gl, -0.5f, 1.5f, slot[iy][0], slot[iy][1]);

        float c = 1.5f;
        for (int itn = 0; itn < 4; ++itn) {
            bool last = (itn == 3);
            // P1: u = G @ y
            launch_gemm(stream, bc, Gh, Gl, C_, NN_, slot[iy][0], slot[iy][1], C_, NN_, C_,
                        1.f, 0.f, 0, 0, 0.f, 0, 0, 0.f,
                        slot[iu][0], slot[iu][1], 0.f, 0.f, 0, 0);
            // P2: t = -0.5*(z@u) - 0.5*c*y
            launch_gemm(stream, bc, slot[iz][0], slot[iz][1], C_, NN_, slot[iu][0], slot[iu][1], C_, NN_, C_,
                        -0.5f, 0.f, slot[iy][0], slot[iy][1], -0.5f * c, 0, 0, 0.f,
                        slot[it][0], slot[it][1], 0.f, 0.f, 0, 0);
            // P3: v = G @ t
            launch_gemm(stream, bc, Gh, Gl, C_, NN_, slot[it][0], slot[it][1], C_, NN_, C_,
                        1.f, 0.f, 0, 0, 0.f, 0, 0, 0.f,
                        slot[iv][0], slot[iv][1], 0.f, 0.f, 0, 0);
            if (!last) {
                // P4: y' = 1.5 y + y@v   -> writes dead u-slot
                launch_gemm(stream, bc, slot[iy][0], slot[iy][1], C_, NN_, slot[iv][0], slot[iv][1], C_, NN_, C_,
                            1.f, 0.f, slot[iy][0], slot[iy][1], 1.5f, 0, 0, 0.f,
                            slot[iu][0], slot[iu][1], 0.f, 0.f, 0, 0);
                // P5: z' = 1.5 z + c t + v@z  -> writes t-slot (t read only as own-idx E2)
                launch_gemm(stream, bc, slot[iv][0], slot[iv][1], C_, NN_, slot[iz][0], slot[iz][1], C_, NN_, C_,
                            1.f, 0.f, slot[iz][0], slot[iz][1], 1.5f, slot[it][0], slot[it][1], c,
                            slot[it][0], slot[it][1], 0.f, 0.f, 0, 0);
                int tmp = iy; iy = iu; iu = tmp;   // y now in old u-slot
                tmp = iz; iz = it; it = tmp;       // z now in old t-slot
                c *= 1.5f;
            }
        }

        // w2 = a^T yf = 1.5*(y a) + v*(y a)   (replaces final P4 GEMM)
        ra_kernel<<<dim3(C_, bc), 128, 0, stream>>>(slot[iy][0], slot[iy][1], avec, r1v, b0);
        w2_kernel<<<dim3(C_, bc), 128, 0, stream>>>(slot[iv][0], slot[iv][1], r1v, w2v, b0);
        svec_kernel<<<dim3(4, bc), 256, 0, stream>>>(w2v, Wh, Wl, svec, b0);
        minmax_kernel<<<bc, 256, 0, stream>>>(svec, ycov, b0);
    }

    size_t n4 = ((size_t)B_ * C_ * D_) / 4;
    scale_kernel<<<(unsigned)((n4 + 255) / 256), 256, 0, stream>>>(X, ycov, out);
}

// Round 5
// 1329.567 us; speedup vs baseline: 1.8452x; 1.8452x over previous
//
#include <hip/hip_runtime.h>

// SOSA forward — round 5: z-only Gram NS recursion + symmetric-tile MFMA GEMM.
// Identity Y_k = A Z_k collapses the coupled NS iteration to one sequence:
//   Gram rep Z_k = c_k I + W^T z W, c_k = 1.5^{k+1};  per iter (3 products):
//     m = g@z;  q = c^2 I + 2c m + m@m;  z' = 1.5 z - 0.5c q - 0.5 q@m
//   iter0 folds into SYRK (m0 = -0.5 g);  iter3 needs only m3 (gate is matvecs).
// All iterates are polynomials in g = WW^T -> symmetric -> compute only the 10
// upper 128^2 tiles, mirror-write via LDS transpose. 4 NN slots + g + W =
// 6.9 MB/batch, NB=32 -> 220 MB (L3-resident). XCD-bijective block swizzle.

typedef unsigned short u16;
typedef unsigned int u32;
typedef short bf16x8 __attribute__((ext_vector_type(8)));
typedef float f32x4 __attribute__((ext_vector_type(4)));

#define B_  64
#define C_  512
#define D_  784
#define DP_ 800
#define NN_ ((size_t)C_ * C_)   // 262144
#define WN_ ((size_t)C_ * DP_)  // 409600
#define NBMAX 32

__device__ inline u16 f2bf(float f) {
    u32 u = __builtin_bit_cast(u32, f);
    u += 0x7fffu + ((u >> 16) & 1u);
    return (u16)(u >> 16);
}
__device__ inline float bf2f(u16 h) {
    u32 u = ((u32)h) << 16;
    return __builtin_bit_cast(float, u);
}

// ---------------------------------------------------------------- small ops
__global__ __launch_bounds__(64) void zero_kernel(float* __restrict__ p, int n) {
    int i = blockIdx.x * 64 + threadIdx.x;
    if (i < n) p[i] = 0.f;
}

__global__ __launch_bounds__(256) void mu_kernel(const float* __restrict__ X,
                                                 float* __restrict__ mu,
                                                 float* __restrict__ ssq) {
    int b = blockIdx.y;
    int i = blockIdx.x * 256 + threadIdx.x;
    float s = 0.f, q = 0.f;
    if (i < D_) {
        const float* xb = X + (size_t)b * C_ * D_ + i;
        for (int c = 0; c < C_; ++c) { float v = xb[(size_t)c * D_]; s += v; q += v * v; }
        mu[b * D_ + i] = s * (1.f / C_);
    }
    __shared__ float red[256];
    red[threadIdx.x] = q;
    __syncthreads();
    for (int off = 128; off > 0; off >>= 1) {
        if (threadIdx.x < off) red[threadIdx.x] += red[threadIdx.x + off];
        __syncthreads();
    }
    if (threadIdx.x == 0) atomicAdd(&ssq[b], red[0]);
}

__global__ __launch_bounds__(256) void rfro_kernel(const float* __restrict__ mu,
                                                   const float* __restrict__ ssq,
                                                   float* __restrict__ rfro) {
    int b = blockIdx.x;
    float q = 0.f;
    for (int i = threadIdx.x; i < D_; i += 256) { float m = mu[b * D_ + i]; q += m * m; }
    __shared__ float red[256];
    red[threadIdx.x] = q;
    __syncthreads();
    for (int off = 128; off > 0; off >>= 1) {
        if (threadIdx.x < off) red[threadIdx.x] += red[threadIdx.x + off];
        __syncthreads();
    }
    if (threadIdx.x == 0) rfro[b] = rsqrtf(ssq[b] - (float)C_ * red[0]);
}

// W = (X - mu) * rfro, split hi/lo bf16, cols 784..799 zero.
__global__ __launch_bounds__(256) void wbuild_kernel(const float* __restrict__ X,
                                                     const float* __restrict__ mu,
                                                     const float* __restrict__ rfro,
                                                     u16* __restrict__ Wh, u16* __restrict__ Wl,
                                                     int b0, int bc) {
    size_t idx = (size_t)blockIdx.x * 256 + threadIdx.x;
    size_t total = (size_t)bc * C_ * (DP_ / 8);
    if (idx >= total) return;
    int ch = (int)(idx % (DP_ / 8));
    size_t rest = idx / (DP_ / 8);
    int c = (int)(rest % C_);
    int bz = (int)(rest / C_);
    int b = b0 + bz;
    int i0 = ch * 8;
    u32 hw[4] = {0, 0, 0, 0}, lw[4] = {0, 0, 0, 0};
    if (i0 < D_) {
        float rf = rfro[b];
        const float* xr = X + ((size_t)b * C_ + c) * D_ + i0;
        const float* mr = mu + (size_t)b * D_ + i0;
#pragma unroll
        for (int e2 = 0; e2 < 4; ++e2) {
            float v0 = (xr[2 * e2] - mr[2 * e2]) * rf;
            float v1 = (xr[2 * e2 + 1] - mr[2 * e2 + 1]) * rf;
            u16 h0 = f2bf(v0), h1 = f2bf(v1);
            u16 l0 = f2bf(v0 - bf2f(h0)), l1 = f2bf(v1 - bf2f(h1));
            hw[e2] = (u32)h0 | ((u32)h1 << 16);
            lw[e2] = (u32)l0 | ((u32)l1 << 16);
        }
    }
    size_t o = ((size_t)bz * C_ + c) * DP_ + i0;
    uint4 ph; ph.x = hw[0]; ph.y = hw[1]; ph.z = hw[2]; ph.w = hw[3];
    uint4 pl; pl.x = lw[0]; pl.y = lw[1]; pl.z = lw[2]; pl.w = lw[3];
    *(uint4*)&Wh[o] = ph;
    *(uint4*)&Wl[o] = pl;
}

// avec[b,c] = (1/d) sum_i W[c,i]
__global__ __launch_bounds__(128) void arowsum_kernel(const u16* __restrict__ Wh,
                                                      const u16* __restrict__ Wl,
                                                      float* __restrict__ avec, int b0) {
    int c = blockIdx.x, bz = blockIdx.y;
    const u16* wh = Wh + ((size_t)bz * C_ + c) * DP_;
    const u16* wl = Wl + ((size_t)bz * C_ + c) * DP_;
    float s = 0.f;
    for (int i = threadIdx.x; i < DP_; i += 128) s += bf2f(wh[i]) + bf2f(wl[i]);
    __shared__ float red[128];
    red[threadIdx.x] = s;
    __syncthreads();
    for (int off = 64; off > 0; off >>= 1) {
        if (threadIdx.x < off) red[threadIdx.x] += red[threadIdx.x + off];
        __syncthreads();
    }
    if (threadIdx.x == 0) avec[(size_t)(b0 + bz) * C_ + c] = red[0] * (1.f / D_);
}

// out[b,c] = sum_j M[c,j] * x[b,j]   (M symmetric, split bf16)
__global__ __launch_bounds__(128) void mv_kernel(const u16* __restrict__ Mh,
                                                 const u16* __restrict__ Ml,
                                                 const float* __restrict__ x,
                                                 float* __restrict__ out, int b0) {
    int c = blockIdx.x, bz = blockIdx.y;
    int b = b0 + bz;
    const u16* ph = Mh + (size_t)bz * NN_ + (size_t)c * C_;
    const u16* pl = Ml + (size_t)bz * NN_ + (size_t)c * C_;
    const float* xb = x + (size_t)b * C_;
    float s = 0.f;
    for (int j = threadIdx.x; j < C_; j += 128) s += (bf2f(ph[j]) + bf2f(pl[j])) * xb[j];
    __shared__ float red[128];
    red[threadIdx.x] = s;
    __syncthreads();
    for (int off = 64; off > 0; off >>= 1) {
        if (threadIdx.x < off) red[threadIdx.x] += red[threadIdx.x + off];
        __syncthreads();
    }
    if (threadIdx.x == 0) out[(size_t)b * C_ + c] = red[0];
}

// out[b,c] = sum_j M[c,j] * (a1 x1 + a2 x2 + a3 x3)[b,j]
__global__ __launch_bounds__(128) void mv3_kernel(const u16* __restrict__ Mh,
                                                  const u16* __restrict__ Ml,
                                                  const float* __restrict__ x1,
                                                  const float* __restrict__ x2,
                                                  const float* __restrict__ x3,
                                                  float a1, float a2, float a3,
                                                  float* __restrict__ out, int b0) {
    int c = blockIdx.x, bz = blockIdx.y;
    int b = b0 + bz;
    const u16* ph = Mh + (size_t)bz * NN_ + (size_t)c * C_;
    const u16* pl = Ml + (size_t)bz * NN_ + (size_t)c * C_;
    const float* p1 = x1 + (size_t)b * C_;
    const float* p2 = x2 + (size_t)b * C_;
    const float* p3 = x3 + (size_t)b * C_;
    float s = 0.f;
    for (int j = threadIdx.x; j < C_; j += 128) {
        float xv = a1 * p1[j] + a2 * p2[j] + a3 * p3[j];
        s += (bf2f(ph[j]) + bf2f(pl[j])) * xv;
    }
    __shared__ float red[128];
    red[threadIdx.x] = s;
    __syncthreads();
    for (int off = 64; off > 0; off >>= 1) {
        if (threadIdx.x < off) red[threadIdx.x] += red[threadIdx.x + off];
        __syncthreads();
    }
    if (threadIdx.x == 0) out[(size_t)b * C_ + c] = red[0];
}

// rvec = ca*a + ct1*t1 + cv1*v1 + cu1*u1 + cu2*u2 + ct3*t3
__global__ __launch_bounds__(256) void rcomb_kernel(const float* __restrict__ a,
                                                    const float* __restrict__ t1,
                                                    const float* __restrict__ v1,
                                                    const float* __restrict__ u1,
                                                    const float* __restrict__ u2,
                                                    const float* __restrict__ t3,
                                                    float ca, float ct1, float cv1,
                                                    float cu1, float cu2, float ct3,
                                                    float* __restrict__ rvec, int b0, int bc) {
    int i = blockIdx.x * 256 + threadIdx.x;
    if (i >= bc * C_) return;
    size_t g = (size_t)b0 * C_ + i;
    rvec[g] = ca * a[g] + ct1 * t1[g] + cv1 * v1[g] + cu1 * u1[g] + cu2 * u2[g] + ct3 * t3[g];
}

// svec[b,j] = sum_c rvec[b,c]*W[c,j]
__global__ __launch_bounds__(256) void svec_kernel(const float* __restrict__ rvec,
                                                   const u16* __restrict__ Wh,
                                                   const u16* __restrict__ Wl,
                                                   float* __restrict__ svec, int b0) {
    int bz = blockIdx.y;
    int j = blockIdx.x * 256 + threadIdx.x;
    if (j >= D_) return;
    const u16* wh = Wh + (size_t)bz * WN_;
    const u16* wl = Wl + (size_t)bz * WN_;
    const float* w = rvec + (size_t)(b0 + bz) * C_;
    float s = 0.f;
    for (int c = 0; c < C_; ++c) s += w[c] * (bf2f(wh[(size_t)c * DP_ + j]) + bf2f(wl[(size_t)c * DP_ + j]));
    svec[(size_t)(b0 + bz) * D_ + j] = s;
}

__global__ __launch_bounds__(256) void minmax_kernel(const float* __restrict__ s,
                                                     float* __restrict__ ycov, int b0) {
    int b = b0 + blockIdx.x;
    const float* sb = s + (size_t)b * D_;
    float mn = 1e30f, mx = -1e30f;
    for (int i = threadIdx.x; i < D_; i += 256) {
        float v = sb[i];
        mn = fminf(mn, v);
        mx = fmaxf(mx, v);
    }
    __shared__ float rmn[256], rmx[256];
    rmn[threadIdx.x] = mn;
    rmx[threadIdx.x] = mx;
    __syncthreads();
    for (int off = 128; off > 0; off >>= 1) {
        if (threadIdx.x < off) {
            rmn[threadIdx.x] = fminf(rmn[threadIdx.x], rmn[threadIdx.x + off]);
            rmx[threadIdx.x] = fmaxf(rmx[threadIdx.x], rmx[threadIdx.x + off]);
        }
        __syncthreads();
    }
    float gmn = rmn[0], gmx = rmx[0];
    float inv = 1.f / (gmx - gmn);
    for (int i = threadIdx.x; i < D_; i += 256)
        ycov[(size_t)b * D_ + i] = (sb[i] - gmn) * inv;
}

__global__ __launch_bounds__(256) void scale_kernel(const float* __restrict__ X,
                                                    const float* __restrict__ ycov,
                                                    float* __restrict__ out) {
    size_t idx = (size_t)blockIdx.x * 256 + threadIdx.x;
    size_t n = idx * 4;
    if (n >= (size_t)B_ * C_ * D_) return;
    int b = (int)(n / ((size_t)C_ * D_));
    int i = (int)(n % D_);
    float4 x4 = *(const float4*)(X + n);
    float4 y4 = *(const float4*)(ycov + (size_t)b * D_ + i);
    float4 o;
    o.x = x4.x * y4.x; o.y = x4.y * y4.y; o.z = x4.z * y4.z; o.w = x4.w * y4.w;
    *(float4*)(out + n) = o;
}

// ---------------------------------------------------------------- MFMA GEMM
// Symmetric-output 512x512 product over 10 upper 128^2 tiles; off-diagonal
// tiles mirror-written via per-wave LDS transpose. Split-3 bf16, BK=32,
// double-buffered LDS, reg-staged prefetch depth 2, XCD-bijective swizzle.
// val = alpha*P + diagv*(r==c) + beta*E1 + gamma*E2
__global__ __launch_bounds__(256, 2) void gemm_ns(
    const u16* __restrict__ Ah, const u16* __restrict__ Al, int ldA, size_t sA,
    const u16* __restrict__ Bh, const u16* __restrict__ Bl, int ldB, size_t sB,
    int K,
    float alpha, float diagv,
    const u16* __restrict__ E1h, const u16* __restrict__ E1l, float beta,
    const u16* __restrict__ E2h, const u16* __restrict__ E2l, float gamma,
    u16* __restrict__ Oh, u16* __restrict__ Ol)
{
    __shared__ u16 lds[2][4][128][36];   // dbuf x {Ah,Al,Bh,Bl} x rows x (32+4 pad)
    // XCD-bijective swizzle (m204): physical -> logical so each XCD owns whole batches
    int nwg = gridDim.x;
    int p = blockIdx.x;
    int qn = nwg >> 3, rn = nwg & 7;
    int xcd = p & 7, o8 = p >> 3;
    int l = (xcd < rn ? xcd * (qn + 1) : rn * (qn + 1) + (xcd - rn) * qn) + o8;
    int bz = l / 10, tid = l - bz * 10;
    const int TRt[10] = {0,0,0,0,1,1,1,2,2,3};
    const int TCt[10] = {0,1,2,3,1,2,3,2,3,3};
    int row0 = TRt[tid] * 128, col0 = TCt[tid] * 128;
    bool mir = (row0 != col0);

    int t = threadIdx.x;
    int lane = t & 63, wid = t >> 6;
    int wr = wid >> 1, wc = wid & 1;
    const u16* pA0 = Ah + (size_t)bz * sA;
    const u16* pA1 = Al + (size_t)bz * sA;
    const u16* pB0 = Bh + (size_t)bz * sB;
    const u16* pB1 = Bl + (size_t)bz * sB;
    int lr = t >> 2, lkc = (t & 3) * 8;
    f32x4 acc[4][4] = {};
    uint4 rg0, rg1, rg2, rg3, rg4, rg5, rg6, rg7;

#define STAGE(k0) do { \
    rg0 = *(const uint4*)&pA0[(size_t)(row0 + lr) * ldA + (k0) + lkc]; \
    rg1 = *(const uint4*)&pA0[(size_t)(row0 + lr + 64) * ldA + (k0) + lkc]; \
    rg2 = *(const uint4*)&pA1[(size_t)(row0 + lr) * ldA + (k0) + lkc]; \
    rg3 = *(const uint4*)&pA1[(size_t)(row0 + lr + 64) * ldA + (k0) + lkc]; \
    rg4 = *(const uint4*)&pB0[(size_t)(col0 + lr) * ldB + (k0) + lkc]; \
    rg5 = *(const uint4*)&pB0[(size_t)(col0 + lr + 64) * ldB + (k0) + lkc]; \
    rg6 = *(const uint4*)&pB1[(size_t)(col0 + lr) * ldB + (k0) + lkc]; \
    rg7 = *(const uint4*)&pB1[(size_t)(col0 + lr + 64) * ldB + (k0) + lkc]; \
} while (0)
#define WLDS(bf) do { \
    *(uint4*)&lds[bf][0][lr][lkc] = rg0; \
    *(uint4*)&lds[bf][0][lr + 64][lkc] = rg1; \
    *(uint4*)&lds[bf][1][lr][lkc] = rg2; \
    *(uint4*)&lds[bf][1][lr + 64][lkc] = rg3; \
    *(uint4*)&lds[bf][2][lr][lkc] = rg4; \
    *(uint4*)&lds[bf][2][lr + 64][lkc] = rg5; \
    *(uint4*)&lds[bf][3][lr][lkc] = rg6; \
    *(uint4*)&lds[bf][3][lr + 64][lkc] = rg7; \
} while (0)

    STAGE(0);
    WLDS(0);
    STAGE(32);
    __syncthreads();

    int nst = K >> 5;
    for (int s = 0; s < nst; ++s) {
        int cur = s & 1;
        if (s + 1 < nst) WLDS(cur ^ 1);
        if (s + 2 < nst) STAGE((s + 2) * 32);
        int koff = (lane >> 4) * 8;
        int fr = lane & 15;
        bf16x8 bhf[4], blf[4];
#pragma unroll
        for (int n = 0; n < 4; ++n) {
            int rB = wc * 64 + n * 16 + fr;
            bhf[n] = *(const bf16x8*)&lds[cur][2][rB][koff];
            blf[n] = *(const bf16x8*)&lds[cur][3][rB][koff];
        }
#pragma unroll
        for (int m = 0; m < 4; ++m) {
            int rA = wr * 64 + m * 16 + fr;
            bf16x8 ah = *(const bf16x8*)&lds[cur][0][rA][koff];
            bf16x8 al = *(const bf16x8*)&lds[cur][1][rA][koff];
#pragma unroll
            for (int n = 0; n < 4; ++n) {
                acc[m][n] = __builtin_amdgcn_mfma_f32_16x16x32_bf16(ah, bhf[n], acc[m][n], 0, 0, 0);
                acc[m][n] = __builtin_amdgcn_mfma_f32_16x16x32_bf16(ah, blf[n], acc[m][n], 0, 0, 0);
                acc[m][n] = __builtin_amdgcn_mfma_f32_16x16x32_bf16(al, bhf[n], acc[m][n], 0, 0, 0);
            }
        }
        if (s + 1 < nst) __syncthreads();
    }
#undef STAGE
#undef WLDS

    // epilogue: row-write + (off-diag) transposed mirror-write via LDS scratch.
    // scr lives in the dbuf half NOT read by the final K-step (no extra barrier).
    size_t eoff = (size_t)bz * NN_;
    const u16* e1h = E1h ? E1h + eoff : (const u16*)0;
    const u16* e1l = E1l ? E1l + eoff : (const u16*)0;
    const u16* e2h = E2h ? E2h + eoff : (const u16*)0;
    const u16* e2l = E2l ? E2l + eoff : (const u16*)0;
    u16* oh = Oh + eoff;
    u16* ol = Ol + eoff;
    int r0g = row0 + wr * 64, c0g = col0 + wc * 64;
    float* scr = (float*)&lds[((nst - 1) & 1) ^ 1][0][0][0] + (size_t)wid * (32 * 68);

#pragma unroll
    for (int p2 = 0; p2 < 2; ++p2) {
#pragma unroll
        for (int a2 = 0; a2 < 2; ++a2) {
            int ai = 2 * p2 + a2;
#pragma unroll
            for (int n = 0; n < 4; ++n) {
                int cg = c0g + n * 16 + (lane & 15);
#pragma unroll
                for (int qi = 0; qi < 4; ++qi) {
                    int rloc = ai * 16 + (lane >> 4) * 4 + qi;
                    int r = r0g + rloc;
                    size_t idx = ((size_t)r << 9) + cg;
                    float P = acc[ai][n][qi];
                    float val = alpha * P;
                    if (r == cg) val += diagv;
                    if (e1h) val += beta * (bf2f(e1h[idx]) + bf2f(e1l[idx]));
                    if (e2h) val += gamma * (bf2f(e2h[idx]) + bf2f(e2l[idx]));
                    u16 h = f2bf(val);
                    oh[idx] = h;
                    ol[idx] = f2bf(val - bf2f(h));
                    if (mir) scr[(rloc - p2 * 32) * 68 + n * 16 + (lane & 15)] = val;
                }
            }
        }
        if (mir) {
#pragma unroll
            for (int g4 = 0; g4 < 4; ++g4) {
                u32 hw[4], lw[4];
#pragma unroll
                for (int e2 = 0; e2 < 4; ++e2) {
                    float v0 = scr[(g4 * 8 + 2 * e2) * 68 + lane];
                    float v1 = scr[(g4 * 8 + 2 * e2 + 1) * 68 + lane];
                    u16 h0 = f2bf(v0), h1 = f2bf(v1);
                    u16 l0 = f2bf(v0 - bf2f(h0)), l1 = f2bf(v1 - bf2f(h1));
                    hw[e2] = (u32)h0 | ((u32)h1 << 16);
                    lw[e2] = (u32)l0 | ((u32)l1 << 16);
                }
                size_t tidx = (size_t)(c0g + lane) * C_ + r0g + p2 * 32 + g4 * 8;
                uint4 ph; ph.x = hw[0]; ph.y = hw[1]; ph.z = hw[2]; ph.w = hw[3];
                uint4 pl; pl.x = lw[0]; pl.y = lw[1]; pl.z = lw[2]; pl.w = lw[3];
                *(uint4*)&oh[tidx] = ph;
                *(uint4*)&ol[tidx] = pl;
            }
        }
    }
}

// ---------------------------------------------------------------- host
static inline void launch_gemm(hipStream_t st, int bc,
    const u16* Ah, const u16* Al, int ldA, size_t sA,
    const u16* Bh, const u16* Bl, int ldB, size_t sB, int K,
    float alpha, float diagv,
    const u16* E1h, const u16* E1l, float beta,
    const u16* E2h, const u16* E2l, float gamma,
    u16* Oh, u16* Ol)
{
    gemm_ns<<<dim3(10 * bc), 256, 0, st>>>(Ah, Al, ldA, sA, Bh, Bl, ldB, sB, K,
        alpha, diagv, E1h, E1l, beta, E2h, E2l, gamma, Oh, Ol);
}

extern "C" void kernel_launch(void* const* d_in, const int* in_sizes, int n_in,
                              void* d_out, int out_size, void* d_ws, size_t ws_size,
                              hipStream_t stream) {
    const float* X = (const float*)d_in[0];
    float* out = (float*)d_out;
    float* hdr = (float*)d_ws;

    float* mu   = hdr;
    float* ssq  = mu + (size_t)B_ * D_;
    float* rfro = ssq + B_;
    float* avec = rfro + B_;
    float* v1v  = avec + (size_t)B_ * C_;
    float* t1v  = v1v + (size_t)B_ * C_;
    float* u1v  = t1v + (size_t)B_ * C_;
    float* u2v  = u1v + (size_t)B_ * C_;
    float* t3v  = u2v + (size_t)B_ * C_;
    float* rvec = t3v + (size_t)B_ * C_;
    float* svec = rvec + (size_t)B_ * C_;
    float* ycov = svec + (size_t)B_ * D_;
    size_t hdrBytes = (size_t)((char*)(ycov + (size_t)B_ * D_) - (char*)hdr);
    size_t matsOff = (hdrBytes + 255) & ~(size_t)255;

    const size_t perBatch = (2 * WN_ + 10 * NN_) * 2;   // bytes (~6.9 MB)
    size_t avail = ws_size > matsOff ? ws_size - matsOff : 0;
    int NB = (int)(avail / perBatch);
    if (NB < 1) NB = 1;
    if (NB > NBMAX) NB = NBMAX;

    u16* q = (u16*)((char*)d_ws + matsOff);
    u16* Wh = q; q += (size_t)NB * WN_;
    u16* Wl = q; q += (size_t)NB * WN_;
    u16* Gh = q; q += (size_t)NB * NN_;
    u16* Gl = q; q += (size_t)NB * NN_;
    u16* slot[4][2];
    for (int s = 0; s < 4; ++s)
        for (int a = 0; a < 2; ++a) { slot[s][a] = q; q += (size_t)NB * NN_; }

    zero_kernel<<<1, 64, 0, stream>>>(ssq, B_);
    mu_kernel<<<dim3((D_ + 255) / 256, B_), 256, 0, stream>>>(X, mu, ssq);
    rfro_kernel<<<B_, 256, 0, stream>>>(mu, ssq, rfro);

    for (int b0 = 0; b0 < B_; b0 += NB) {
        int bc = (B_ - b0 < NB) ? (B_ - b0) : NB;

        size_t wbTotal = (size_t)bc * C_ * (DP_ / 8);
        wbuild_kernel<<<(unsigned)((wbTotal + 255) / 256), 256, 0, stream>>>(X, mu, rfro, Wh, Wl, b0, bc);
        arowsum_kernel<<<dim3(C_, bc), 128, 0, stream>>>(Wh, Wl, avec, b0);

        // SYRK: g = W W^T
        launch_gemm(stream, bc, Wh, Wl, DP_, WN_, Wh, Wl, DP_, WN_, DP_,
                    1.f, 0.f, 0, 0, 0.f, 0, 0, 0.f, Gh, Gl);
        // G1 (iter0 P2, m0 = -0.5g folded): q0 = 0.25*(g@g) - 1.5 g + 2.25 I -> S2
        launch_gemm(stream, bc, Gh, Gl, C_, NN_, Gh, Gl, C_, NN_, C_,
                    0.25f, 2.25f, Gh, Gl, -1.5f, 0, 0, 0.f,
                    slot[2][0], slot[2][1]);
        // G2 (iter0 P3): z1 = 0.25*(q0@g) - 0.75 q0 - 0.75 I -> S3
        launch_gemm(stream, bc, slot[2][0], slot[2][1], C_, NN_, Gh, Gl, C_, NN_, C_,
                    0.25f, -0.75f, slot[2][0], slot[2][1], -0.75f, 0, 0, 0.f,
                    slot[3][0], slot[3][1]);

        int iz = 3, im = 1, iq = 2, ifr = 0;
        float c = 2.25f;                      // c_1
        for (int k = 1; k <= 2; ++k) {
            // P1: m = g@z
            launch_gemm(stream, bc, Gh, Gl, C_, NN_, slot[iz][0], slot[iz][1], C_, NN_, C_,
                        1.f, 0.f, 0, 0, 0.f, 0, 0, 0.f,
                        slot[im][0], slot[im][1]);
            // P2: q = m@m + 2c m + c^2 I
            launch_gemm(stream, bc, slot[im][0], slot[im][1], C_, NN_, slot[im][0], slot[im][1], C_, NN_, C_,
                        1.f, c * c, slot[im][0], slot[im][1], 2.f * c, 0, 0, 0.f,
                        slot[iq][0], slot[iq][1]);
            // P3: z' = -0.5*(q@m) + 1.5 z - 0.5c q
            launch_gemm(stream, bc, slot[iq][0], slot[iq][1], C_, NN_, slot[im][0], slot[im][1], C_, NN_, C_,
                        -0.5f, 0.f, slot[iz][0], slot[iz][1], 1.5f, slot[iq][0], slot[iq][1], -0.5f * c,
                        slot[ifr][0], slot[ifr][1]);
            int tmp = iz; iz = ifr; ifr = tmp;
            c *= 1.5f;
        }
        // c == c_3 = 5.0625.  iter3 P1 only: m3 = g@z3
        launch_gemm(stream, bc, Gh, Gl, C_, NN_, slot[iz][0], slot[iz][1], C_, NN_, C_,
                    1.f, 0.f, 0, 0, 0.f, 0, 0, 0.f,
                    slot[im][0], slot[im][1]);

        // gate matvec chain: r = c4 a + 1.5 z3 v1 - 0.5 c3 q3 v1 - 0.5 m3 q3 v1
        float c3 = c, c4 = 1.5f * c;
        mv_kernel<<<dim3(C_, bc), 128, 0, stream>>>(Gh, Gl, avec, v1v, b0);
        mv_kernel<<<dim3(C_, bc), 128, 0, stream>>>(slot[iz][0], slot[iz][1], v1v, t1v, b0);
        mv_kernel<<<dim3(C_, bc), 128, 0, stream>>>(slot[im][0], slot[im][1], v1v, u1v, b0);
        mv_kernel<<<dim3(C_, bc), 128, 0, stream>>>(slot[im][0], slot[im][1], u1v, u2v, b0);
        mv3_kernel<<<dim3(C_, bc), 128, 0, stream>>>(slot[im][0], slot[im][1], v1v, u1v, u2v,
                                                     c3 * c3, 2.f * c3, 1.f, t3v, b0);
        rcomb_kernel<<<(bc * C_ + 255) / 256, 256, 0, stream>>>(
            avec, t1v, v1v, u1v, u2v, t3v,
            c4, 1.5f, -0.5f * c3 * c3 * c3, -c3 * c3, -0.5f * c3, -0.5f,
            rvec, b0, bc);
        svec_kernel<<<dim3(4, bc), 256, 0, stream>>>(rvec, Wh, Wl, svec, b0);
        minmax_kernel<<<bc, 256, 0, stream>>>(svec, ycov, b0);
    }

    size_t n4 = ((size_t)B_ * C_ * D_) / 4;
    scale_kernel<<<(unsigned)((n4 + 255) / 256), 256, 0, stream>>>(X, ycov, out);
}